// Round 3
// baseline (350.993 us; speedup 1.0000x reference)
//
#include <hip/hip_runtime.h>
#include <hip/hip_bf16.h>

// Problem dims (fixed by setup_inputs)
#define NODES 8192
#define DIM   200
#define NEDGE 4096
#define DEGREE 16
#define NB    4
#define NNODE 2048   // nodes per graph = NODES/NB
#define HD    128

// ---- column sum of x (for alpha) ----
__global__ void k_colsum(const float* __restrict__ x, float* __restrict__ colsum) {
    int d = blockIdx.x;          // 0..DIM-1
    int t = threadIdx.x;
    float s = 0.f;
    for (int n = t; n < NODES; n += 256) s += x[n * DIM + d];
    __shared__ float red[256];
    red[t] = s; __syncthreads();
    for (int off = 128; off > 0; off >>= 1) {
        if (t < off) red[t] += red[t + off];
        __syncthreads();
    }
    if (t == 0) colsum[d] = red[0];
}

// ---- alpha = sigmoid(mean(x) @ gate_w + gate_b) ----
__global__ void k_alpha(const float* __restrict__ colsum, const float* __restrict__ gate_w,
                        const float* __restrict__ gate_b, float* __restrict__ alpha) {
    int t = threadIdx.x;
    float s = (t < DIM) ? colsum[t] * gate_w[t] : 0.f;
    __shared__ float red[256];
    red[t] = s; __syncthreads();
    for (int off = 128; off > 0; off >>= 1) {
        if (t < off) red[t] += red[t + off];
        __syncthreads();
    }
    if (t == 0) {
        float z = red[0] / (float)NODES + gate_b[0];
        alpha[0] = 1.0f / (1.0f + expf(-z));
    }
}

// ---- out = x @ W, one row per block, staged fp32 into d_out ----
__global__ void k_xw(const float* __restrict__ x, const float* __restrict__ W,
                     float* __restrict__ outf) {
    __shared__ float sx[DIM];
    int n = blockIdx.x, t = threadIdx.x;
    if (t < DIM) sx[t] = x[n * DIM + t];
    __syncthreads();
    if (t < DIM) {
        float acc = 0.f;
        for (int k = 0; k < DIM; k++) acc += sx[k] * W[k * DIM + t];
        outf[n * DIM + t] = acc;
    }
}

// ---- per-edge dedupe + node-degree counts (set semantics!) ----
__global__ void k_count(const int* __restrict__ en, int* __restrict__ cnt,
                        int* __restrict__ emask) {
    int e = blockIdx.x * blockDim.x + threadIdx.x;
    if (e >= NEDGE) return;
    int idx[DEGREE];
#pragma unroll
    for (int i = 0; i < DEGREE; i++) idx[i] = en[e * DEGREE + i];
    int mask = 0;
#pragma unroll
    for (int i = 0; i < DEGREE; i++) {
        bool uniq = true;
        for (int j = 0; j < i; j++) uniq = uniq && (idx[j] != idx[i]);
        if (uniq) { mask |= (1 << i); atomicAdd(&cnt[idx[i]], 1); }
    }
    emask[e] = mask;
}

// ---- dv = 1/sqrt(Dv + eps) from counts ----
__global__ void k_dv(const int* __restrict__ cnt, float* __restrict__ dv) {
    int n = blockIdx.x * blockDim.x + threadIdx.x;
    if (n < NODES) dv[n] = 1.0f / sqrtf((float)cnt[n] * (1.0f / 16.0f) + 1e-8f);
}

// ---- exclusive prefix sum over cnt -> off[NODES+1]; also copy to cursor ----
__global__ void k_scan(const int* __restrict__ cnt, int* __restrict__ off,
                       int* __restrict__ cursor) {
    __shared__ int tsum[1024];
    __shared__ int tpre[1025];
    int t = threadIdx.x;                 // 1024 threads, 8 elems each
    int base = t * 8;
    int local[8];
    int s = 0;
#pragma unroll
    for (int i = 0; i < 8; i++) { local[i] = cnt[base + i]; s += local[i]; }
    tsum[t] = s;
    __syncthreads();
    if (t == 0) {
        tpre[0] = 0;
        for (int j = 0; j < 1024; j++) tpre[j + 1] = tpre[j] + tsum[j];
    }
    __syncthreads();
    int run = tpre[t];
#pragma unroll
    for (int i = 0; i < 8; i++) {
        off[base + i] = run;
        cursor[base + i] = run;
        run += local[i];
    }
    if (t == 1023) off[NODES] = run;
}

// ---- fill node->edge lists via int atomics on cursor ----
__global__ void k_fill(const int* __restrict__ en, const int* __restrict__ emask,
                       int* __restrict__ cursor, int* __restrict__ elist) {
    int e = blockIdx.x * blockDim.x + threadIdx.x;
    if (e >= NEDGE) return;
    int m = emask[e];
#pragma unroll
    for (int i = 0; i < DEGREE; i++) {
        if ((m >> i) & 1) {
            int n = en[e * DEGREE + i];
            int p = atomicAdd(&cursor[n], 1);
            elist[p] = e;
        }
    }
}

// ---- per-edge weighted gather: tE[e,:] = de[e] * sum_{i in uniq(e)} dv[m_i]*outf[m_i,:] ----
__global__ void k_tE(const int* __restrict__ en, const int* __restrict__ emask,
                     const float* __restrict__ dv, const float* __restrict__ outf,
                     float* __restrict__ tE) {
    __shared__ int   sidx[DEGREE];
    __shared__ float sdv[DEGREE];
    __shared__ int   smask;
    __shared__ float sde;
    int e = blockIdx.x, t = threadIdx.x;
    if (t < DEGREE) {
        int n = en[e * DEGREE + t];
        sidx[t] = n;
        sdv[t] = dv[n];
    }
    if (t == 0) {
        int m = emask[e];
        smask = m;
        float De = (float)__popc(m) * (1.0f / 16.0f);
        sde = 1.0f / (De + 1e-8f);
    }
    __syncthreads();
    if (t < DIM) {
        int m = smask;
        float acc = 0.f;
#pragma unroll
        for (int i = 0; i < DEGREE; i++)
            if (m & (1 << i)) acc += sdv[i] * outf[sidx[i] * DIM + t];
        tE[e * DIM + t] = sde * acc;
    }
}

// ---- tiny per-graph tensors: tp, v, attO = v@aow+aob, attg = attO@fgw[128:]+fgb ----
// q/k/scores/softmax are dead code: kv_len==1 -> softmax==1 -> att = v broadcast.
__global__ void k_small(const float* __restrict__ text, const float* __restrict__ text_w,
                        const float* __restrict__ text_b, const float* __restrict__ in_w,
                        const float* __restrict__ in_b, const float* __restrict__ aow,
                        const float* __restrict__ aob, const float* __restrict__ fgw,
                        const float* __restrict__ fgb, float* __restrict__ attO,
                        float* __restrict__ attg) {
    __shared__ float st[DIM];
    __shared__ float stp[HD];
    __shared__ float sv[HD];
    __shared__ float so[HD];
    int t = threadIdx.x;  // 128 threads
    for (int b = 0; b < NB; b++) {
        for (int d = t; d < DIM; d += HD) st[d] = text[b * DIM + d];
        __syncthreads();
        float acc = text_b[t];
        for (int k = 0; k < DIM; k++) acc += st[k] * text_w[k * HD + t];
        stp[t] = acc;
        __syncthreads();
        // v = tp @ in_w[:, 2H:3H] + in_b[2H:3H]
        acc = in_b[2 * HD + t];
        for (int j = 0; j < HD; j++) acc += stp[j] * in_w[j * 3 * HD + 2 * HD + t];
        sv[t] = acc;
        __syncthreads();
        acc = aob[t];
        for (int j = 0; j < HD; j++) acc += sv[j] * aow[j * HD + t];
        so[t] = acc;
        attO[b * HD + t] = acc;
        __syncthreads();
        acc = fgb[t];
        for (int j = 0; j < HD; j++) acc += so[j] * fgw[(HD + j) * HD + t];
        attg[b * HD + t] = acc;
        __syncthreads();
    }
}

// ---- fused tail: hyper gather -> gnn_feat -> gp -> gate -> fused -> out proj ----
// outbuf == d_out: holds outf (fp32 x@W) on entry for row n; overwritten with
// the final output at the end. Only block n touches row n -> no race.
__global__ void k_tail(float* __restrict__ outbuf, const float* __restrict__ tE,
                       const float* __restrict__ dv, const int* __restrict__ off,
                       const int* __restrict__ elist, const float* __restrict__ alpha,
                       const float* __restrict__ bias, const float* __restrict__ gnn_w,
                       const float* __restrict__ gnn_b, const float* __restrict__ fgw,
                       const float* __restrict__ attO, const float* __restrict__ attg,
                       const float* __restrict__ opw, const float* __restrict__ opb) {
    __shared__ float sg[DIM];
    __shared__ float sgp[HD];
    __shared__ float sf[HD];
    int n = blockIdx.x;
    int b = n >> 11;  // NNODE = 2048
    int t = threadIdx.x;
    float a = alpha[0];
    int j0 = off[n], j1 = off[n + 1];
    if (t < DIM) {
        float own = outbuf[n * DIM + t];
        float hyp = 0.f;
        for (int j = j0; j < j1; j++) {
            int e = elist[j];
            hyp += tE[e * DIM + t];
        }
        hyp *= dv[n] * (1.0f / 256.0f);
        sg[t] = a * own + (1.0f - a) * hyp + bias[t];
    }
    __syncthreads();
    if (t < HD) {
        float acc = gnn_b[t];
        for (int k = 0; k < DIM; k++) acc += sg[k] * gnn_w[k * HD + t];
        sgp[t] = acc;
    }
    __syncthreads();
    if (t < HD) {
        float acc = attg[b * HD + t];  // includes fgate_b and attO@fgw[128:]
        for (int j = 0; j < HD; j++) acc += sgp[j] * fgw[j * HD + t];
        float g = 1.0f / (1.0f + expf(-acc));
        sf[t] = g * sgp[t] + (1.0f - g) * attO[b * HD + t];
    }
    __syncthreads();
    if (t < DIM) {
        float acc = opb[t];
        for (int j = 0; j < HD; j++) acc += sf[j] * opw[j * DIM + t];
        outbuf[n * DIM + t] = acc;
    }
}

extern "C" void kernel_launch(void* const* d_in, const int* in_sizes, int n_in,
                              void* d_out, int out_size, void* d_ws, size_t ws_size,
                              hipStream_t stream) {
    const float* x      = (const float*)d_in[0];
    const float* text   = (const float*)d_in[1];
    const float* W      = (const float*)d_in[2];
    const float* bias   = (const float*)d_in[3];
    const float* gate_w = (const float*)d_in[4];
    const float* gate_b = (const float*)d_in[5];
    const float* gnn_w  = (const float*)d_in[6];
    const float* gnn_b  = (const float*)d_in[7];
    const float* text_w = (const float*)d_in[8];
    const float* text_b = (const float*)d_in[9];
    const float* in_w   = (const float*)d_in[10];
    const float* in_b   = (const float*)d_in[11];
    const float* aow    = (const float*)d_in[12];
    const float* aob    = (const float*)d_in[13];
    const float* fgw    = (const float*)d_in[14];
    const float* fgb    = (const float*)d_in[15];
    const float* opw    = (const float*)d_in[16];
    const float* opb    = (const float*)d_in[17];
    const int*   en     = (const int*)d_in[18];
    float* out = (float*)d_out;

    // Scratch layout (~3.7 MB; d_out doubles as the fp32 x@W staging buffer)
    char* p = (char*)d_ws;
    float* tE     = (float*)p; p += (size_t)NEDGE * DIM * sizeof(float);
    float* dv     = (float*)p; p += NODES * sizeof(float);
    float* colsum = (float*)p; p += DIM * sizeof(float);
    float* alpha  = (float*)p; p += sizeof(float);
    float* attO   = (float*)p; p += NB * HD * sizeof(float);
    float* attg   = (float*)p; p += NB * HD * sizeof(float);
    int*   cnt    = (int*)p;   p += NODES * sizeof(int);
    int*   off    = (int*)p;   p += (NODES + 1) * sizeof(int);
    int*   cursor = (int*)p;   p += NODES * sizeof(int);
    int*   emask  = (int*)p;   p += NEDGE * sizeof(int);
    int*   elist  = (int*)p;   p += (size_t)NEDGE * DEGREE * sizeof(int);

    hipMemsetAsync(cnt, 0, NODES * sizeof(int), stream);

    k_colsum<<<DIM, 256, 0, stream>>>(x, colsum);
    k_alpha<<<1, 256, 0, stream>>>(colsum, gate_w, gate_b, alpha);
    k_xw<<<NODES, 256, 0, stream>>>(x, W, out);
    k_count<<<(NEDGE + 255) / 256, 256, 0, stream>>>(en, cnt, emask);
    k_dv<<<(NODES + 255) / 256, 256, 0, stream>>>(cnt, dv);
    k_scan<<<1, 1024, 0, stream>>>(cnt, off, cursor);
    k_fill<<<(NEDGE + 255) / 256, 256, 0, stream>>>(en, emask, cursor, elist);
    k_small<<<1, 128, 0, stream>>>(text, text_w, text_b, in_w, in_b, aow, aob, fgw, fgb,
                                   attO, attg);
    k_tE<<<NEDGE, 256, 0, stream>>>(en, emask, dv, out, tE);
    k_tail<<<NODES, 256, 0, stream>>>(out, tE, dv, off, elist, alpha, bias, gnn_w, gnn_b,
                                      fgw, attO, attg, opw, opb);
}

// Round 4
// 309.143 us; speedup vs baseline: 1.1354x; 1.1354x over previous
//
#include <hip/hip_runtime.h>
#include <hip/hip_bf16.h>

// Problem dims (fixed by setup_inputs)
#define NODES 8192
#define DIM   200
#define NEDGE 4096
#define DEGREE 16
#define NB    4
#define NNODE 2048   // nodes per graph = NODES/NB
#define HD    128
#define MT    32     // row tile for the big GEMM kernels

// ---- column sum of x (for alpha) ----
__global__ void k_colsum(const float* __restrict__ x, float* __restrict__ colsum) {
    int d = blockIdx.x;          // 0..DIM-1
    int t = threadIdx.x;
    float s = 0.f;
    for (int n = t; n < NODES; n += 256) s += x[n * DIM + d];
    __shared__ float red[256];
    red[t] = s; __syncthreads();
    for (int off = 128; off > 0; off >>= 1) {
        if (t < off) red[t] += red[t + off];
        __syncthreads();
    }
    if (t == 0) colsum[d] = red[0];
}

// ---- alpha = sigmoid(mean(x) @ gate_w + gate_b) ----
__global__ void k_alpha(const float* __restrict__ colsum, const float* __restrict__ gate_w,
                        const float* __restrict__ gate_b, float* __restrict__ alpha) {
    int t = threadIdx.x;
    float s = (t < DIM) ? colsum[t] * gate_w[t] : 0.f;
    __shared__ float red[256];
    red[t] = s; __syncthreads();
    for (int off = 128; off > 0; off >>= 1) {
        if (t < off) red[t] += red[t + off];
        __syncthreads();
    }
    if (t == 0) {
        float z = red[0] / (float)NODES + gate_b[0];
        alpha[0] = 1.0f / (1.0f + expf(-z));
    }
}

// ---- precompute: Wg = W @ gnn_w (200x128), bg = bias@gnn_w + gnn_b,
// ---- and (block 201) the tiny per-graph text-path tensors attO/attg.
// q/k/scores/softmax are dead code: kv_len==1 -> softmax==1 -> att = v broadcast.
__global__ void k_prep(const float* __restrict__ W, const float* __restrict__ gnn_w,
                       const float* __restrict__ bias, const float* __restrict__ gnn_b,
                       const float* __restrict__ text, const float* __restrict__ text_w,
                       const float* __restrict__ text_b, const float* __restrict__ in_w,
                       const float* __restrict__ in_b, const float* __restrict__ aow,
                       const float* __restrict__ aob, const float* __restrict__ fgw,
                       const float* __restrict__ fgb, float* __restrict__ Wg,
                       float* __restrict__ bg, float* __restrict__ attO,
                       float* __restrict__ attg) {
    int t = threadIdx.x;  // 128 threads
    if (blockIdx.x < DIM + 1) {
        int r = blockIdx.x;
        const float* vec = (r < DIM) ? &W[r * DIM] : bias;
        float acc = 0.f;
        for (int k = 0; k < DIM; k++) acc += vec[k] * gnn_w[k * HD + t];
        if (r < DIM) Wg[r * HD + t] = acc;
        else bg[t] = acc + gnn_b[t];
        return;
    }
    // block DIM+1: text path (4 graphs)
    __shared__ float st[DIM];
    __shared__ float stp[HD];
    __shared__ float sv[HD];
    __shared__ float so[HD];
    for (int b = 0; b < NB; b++) {
        for (int d = t; d < DIM; d += HD) st[d] = text[b * DIM + d];
        __syncthreads();
        float acc = text_b[t];
        for (int k = 0; k < DIM; k++) acc += st[k] * text_w[k * HD + t];
        stp[t] = acc;
        __syncthreads();
        acc = in_b[2 * HD + t];
        for (int j = 0; j < HD; j++) acc += stp[j] * in_w[j * 3 * HD + 2 * HD + t];
        sv[t] = acc;
        __syncthreads();
        acc = aob[t];
        for (int j = 0; j < HD; j++) acc += sv[j] * aow[j * HD + t];
        so[t] = acc;
        attO[b * HD + t] = acc;
        __syncthreads();
        acc = fgb[t];
        for (int j = 0; j < HD; j++) acc += so[j] * fgw[(HD + j) * HD + t];
        attg[b * HD + t] = acc;
        __syncthreads();
    }
}

// ---- out2 = x @ Wg  [NODES x HD], register-blocked tile GEMM ----
__global__ void k_xwg(const float* __restrict__ x, const float* __restrict__ Wg,
                      float* __restrict__ out2) {
    __shared__ float sx[MT][DIM];
    int bm = blockIdx.x * MT;
    int t = threadIdx.x;
    for (int i = t; i < MT * DIM; i += 256) sx[i / DIM][i % DIM] = x[bm * DIM + i];
    __syncthreads();
    int c = t & 127, rg = t >> 7;     // 2 row-groups x 128 cols
    float acc[MT / 2];
#pragma unroll
    for (int i = 0; i < MT / 2; i++) acc[i] = 0.f;
    for (int k = 0; k < DIM; k++) {
        float w = Wg[k * HD + c];
#pragma unroll
        for (int i = 0; i < MT / 2; i++) acc[i] += sx[rg + 2 * i][k] * w;
    }
#pragma unroll
    for (int i = 0; i < MT / 2; i++) out2[(bm + rg + 2 * i) * HD + c] = acc[i];
}

// ---- per-edge dedupe + node-degree counts (set semantics!) ----
__global__ void k_count(const int* __restrict__ en, int* __restrict__ cnt,
                        int* __restrict__ emask) {
    int e = blockIdx.x * blockDim.x + threadIdx.x;
    if (e >= NEDGE) return;
    int idx[DEGREE];
#pragma unroll
    for (int i = 0; i < DEGREE; i++) idx[i] = en[e * DEGREE + i];
    int mask = 0;
#pragma unroll
    for (int i = 0; i < DEGREE; i++) {
        bool uniq = true;
        for (int j = 0; j < i; j++) uniq = uniq && (idx[j] != idx[i]);
        if (uniq) { mask |= (1 << i); atomicAdd(&cnt[idx[i]], 1); }
    }
    emask[e] = mask;
}

// ---- parallel scan over cnt -> off[NODES+1], cursor copy, dv = 1/sqrt(cnt/16+eps) ----
__global__ void k_scan(const int* __restrict__ cnt, int* __restrict__ off,
                       int* __restrict__ cursor, float* __restrict__ dv) {
    __shared__ int buf[1024];
    int t = threadIdx.x;                 // 1024 threads, 8 elems each
    int base = t * 8;
    int local[8];
    int s = 0;
#pragma unroll
    for (int i = 0; i < 8; i++) { local[i] = cnt[base + i]; s += local[i]; }
    buf[t] = s;
    __syncthreads();
    // Hillis-Steele inclusive scan over the 1024 per-thread sums
    for (int d = 1; d < 1024; d <<= 1) {
        int v = (t >= d) ? buf[t - d] : 0;
        __syncthreads();
        buf[t] += v;
        __syncthreads();
    }
    int run = buf[t] - s;                // exclusive base for this thread's chunk
#pragma unroll
    for (int i = 0; i < 8; i++) {
        off[base + i] = run;
        cursor[base + i] = run;
        dv[base + i] = 1.0f / sqrtf((float)local[i] * (1.0f / 16.0f) + 1e-8f);
        run += local[i];
    }
    if (t == 1023) off[NODES] = run;
}

// ---- fill node->edge lists via int atomics on cursor ----
__global__ void k_fill(const int* __restrict__ en, const int* __restrict__ emask,
                       int* __restrict__ cursor, int* __restrict__ elist) {
    int e = blockIdx.x * blockDim.x + threadIdx.x;
    if (e >= NEDGE) return;
    int m = emask[e];
#pragma unroll
    for (int i = 0; i < DEGREE; i++) {
        if ((m >> i) & 1) {
            int n = en[e * DEGREE + i];
            int p = atomicAdd(&cursor[n], 1);
            elist[p] = e;
        }
    }
}

// ---- tE[e,:] = de[e] * sum_{i in uniq(e)} dv[m_i] * out2[m_i,:]   (128-dim) ----
__global__ void k_tE(const int* __restrict__ en, const int* __restrict__ emask,
                     const float* __restrict__ dv, const float* __restrict__ out2,
                     float* __restrict__ tE) {
    int e = blockIdx.x * 2 + (threadIdx.x >> 7);
    int c = threadIdx.x & 127;
    int m = emask[e];
    float De = (float)__popc(m) * (1.0f / 16.0f);
    float de = 1.0f / (De + 1e-8f);
    float acc = 0.f;
#pragma unroll
    for (int i = 0; i < DEGREE; i++) {
        if ((m >> i) & 1) {
            int nd = en[e * DEGREE + i];
            acc += dv[nd] * out2[nd * HD + c];
        }
    }
    tE[e * HD + c] = de * acc;
}

// ---- fused tail over 32-row tiles:
// gp = a*out2 + (1-a)*dv/256 * sum tE + bg  -> gate -> fused -> out = fused@opw + opb
__global__ void k_tail(const float* __restrict__ out2, const float* __restrict__ tE,
                       const float* __restrict__ dv, const int* __restrict__ off,
                       const int* __restrict__ elist, const float* __restrict__ alpha,
                       const float* __restrict__ bg, const float* __restrict__ fgw,
                       const float* __restrict__ attO, const float* __restrict__ attg,
                       const float* __restrict__ opw, const float* __restrict__ opb,
                       float* __restrict__ out) {
    __shared__ float sgp[MT][HD];
    int bm = blockIdx.x * MT;
    int b = bm >> 11;                    // graph id (NNODE=2048 divides tiles evenly)
    int t = threadIdx.x;
    int c = t & 127, rg = t >> 7;
    float a = alpha[0];
    float bgc = bg[c];
    // phase 1: gp rows into LDS
#pragma unroll
    for (int i = 0; i < MT / 2; i++) {
        int r = rg + 2 * i;
        int n = bm + r;
        int j0 = off[n], j1 = off[n + 1];
        float hyp = 0.f;
        for (int j = j0; j < j1; j++) hyp += tE[elist[j] * HD + c];
        hyp *= dv[n] * (1.0f / 256.0f);
        sgp[r][c] = a * out2[n * HD + c] + (1.0f - a) * hyp + bgc;
    }
    __syncthreads();
    // phase 2: gate logits (weight element reused across 16 rows in registers)
    float ao = attO[b * HD + c];
    float ag = attg[b * HD + c];
    float acc[MT / 2];
#pragma unroll
    for (int i = 0; i < MT / 2; i++) acc[i] = ag;
    for (int j = 0; j < HD; j++) {
        float w = fgw[j * HD + c];
#pragma unroll
        for (int i = 0; i < MT / 2; i++) acc[i] += sgp[rg + 2 * i][j] * w;
    }
    __syncthreads();   // all sgp reads done; safe to overwrite in place
    // phase 3: fused = g*gp + (1-g)*attO, in place
#pragma unroll
    for (int i = 0; i < MT / 2; i++) {
        int r = rg + 2 * i;
        float g = 1.0f / (1.0f + expf(-acc[i]));
        sgp[r][c] = g * sgp[r][c] + (1.0f - g) * ao;
    }
    __syncthreads();
    // phase 4: out = fused @ opw + opb  (threads 0..199 own one output col each)
    if (t < DIM) {
        float accO[MT];
        float ob = opb[t];
#pragma unroll
        for (int i = 0; i < MT; i++) accO[i] = ob;
        for (int j = 0; j < HD; j++) {
            float w = opw[j * DIM + t];
#pragma unroll
            for (int i = 0; i < MT; i++) accO[i] += sgp[i][j] * w;
        }
#pragma unroll
        for (int i = 0; i < MT; i++) out[(bm + i) * DIM + t] = accO[i];
    }
}

extern "C" void kernel_launch(void* const* d_in, const int* in_sizes, int n_in,
                              void* d_out, int out_size, void* d_ws, size_t ws_size,
                              hipStream_t stream) {
    const float* x      = (const float*)d_in[0];
    const float* text   = (const float*)d_in[1];
    const float* W      = (const float*)d_in[2];
    const float* bias   = (const float*)d_in[3];
    const float* gate_w = (const float*)d_in[4];
    const float* gate_b = (const float*)d_in[5];
    const float* gnn_w  = (const float*)d_in[6];
    const float* gnn_b  = (const float*)d_in[7];
    const float* text_w = (const float*)d_in[8];
    const float* text_b = (const float*)d_in[9];
    const float* in_w   = (const float*)d_in[10];
    const float* in_b   = (const float*)d_in[11];
    const float* aow    = (const float*)d_in[12];
    const float* aob    = (const float*)d_in[13];
    const float* fgw    = (const float*)d_in[14];
    const float* fgb    = (const float*)d_in[15];
    const float* opw    = (const float*)d_in[16];
    const float* opb    = (const float*)d_in[17];
    const int*   en     = (const int*)d_in[18];
    float* out = (float*)d_out;

    // Scratch layout (~6.6 MB)
    char* p = (char*)d_ws;
    float* out2   = (float*)p; p += (size_t)NODES * HD * sizeof(float);   // 4 MB
    float* tE     = (float*)p; p += (size_t)NEDGE * HD * sizeof(float);   // 2 MB
    float* Wg     = (float*)p; p += DIM * HD * sizeof(float);
    float* dv     = (float*)p; p += NODES * sizeof(float);
    float* colsum = (float*)p; p += DIM * sizeof(float);
    float* alpha  = (float*)p; p += sizeof(float);
    float* bg     = (float*)p; p += HD * sizeof(float);
    float* attO   = (float*)p; p += NB * HD * sizeof(float);
    float* attg   = (float*)p; p += NB * HD * sizeof(float);
    int*   cnt    = (int*)p;   p += NODES * sizeof(int);
    int*   off    = (int*)p;   p += (NODES + 1) * sizeof(int);
    int*   cursor = (int*)p;   p += NODES * sizeof(int);
    int*   emask  = (int*)p;   p += NEDGE * sizeof(int);
    int*   elist  = (int*)p;   p += (size_t)NEDGE * DEGREE * sizeof(int);

    hipMemsetAsync(cnt, 0, NODES * sizeof(int), stream);

    k_colsum<<<DIM, 256, 0, stream>>>(x, colsum);
    k_alpha<<<1, 256, 0, stream>>>(colsum, gate_w, gate_b, alpha);
    k_prep<<<DIM + 2, 128, 0, stream>>>(W, gnn_w, bias, gnn_b, text, text_w, text_b,
                                        in_w, in_b, aow, aob, fgw, fgb,
                                        Wg, bg, attO, attg);
    k_count<<<(NEDGE + 255) / 256, 256, 0, stream>>>(en, cnt, emask);
    k_scan<<<1, 1024, 0, stream>>>(cnt, off, cursor, dv);
    k_fill<<<(NEDGE + 255) / 256, 256, 0, stream>>>(en, emask, cursor, elist);
    k_xwg<<<NODES / MT, 256, 0, stream>>>(x, Wg, out2);
    k_tE<<<NEDGE / 2, 256, 0, stream>>>(en, emask, dv, out2, tE);
    k_tail<<<NODES / MT, 256, 0, stream>>>(out2, tE, dv, off, elist, alpha, bg, fgw,
                                           attO, attg, opw, opb, out);
}

// Round 5
// 213.622 us; speedup vs baseline: 1.6431x; 1.4471x over previous
//
#include <hip/hip_runtime.h>
#include <hip/hip_bf16.h>

// Problem dims (fixed by setup_inputs)
#define NODES 8192
#define DIM   200
#define NEDGE 4096
#define DEGREE 16
#define NB    4
#define NNODE 2048   // nodes per graph = NODES/NB
#define HD    128
#define MT    8      // row tile (8 rows/block -> 1024 blocks -> 4 wg/CU)
#define ECAP  64     // LDS cap for per-row edge list (avg 8, Poisson tail << 64)

// ---- k_front: colsum (blocks 0..255) + edge count/dedupe (256..271)
// ----          + Wg = W@gnn_w rows (272..371) + bg (372) + text path (373)
__global__ void k_front(const float* __restrict__ x, const int* __restrict__ en,
                        const float* __restrict__ W, const float* __restrict__ gnn_w,
                        const float* __restrict__ bias, const float* __restrict__ gnn_b,
                        const float* __restrict__ text, const float* __restrict__ text_w,
                        const float* __restrict__ text_b, const float* __restrict__ in_w,
                        const float* __restrict__ in_b, const float* __restrict__ aow,
                        const float* __restrict__ aob, const float* __restrict__ fgw,
                        const float* __restrict__ fgb, float* __restrict__ colsum,
                        int* __restrict__ cnt, int* __restrict__ emask,
                        float* __restrict__ Wg, float* __restrict__ bg,
                        float* __restrict__ attO, float* __restrict__ attg) {
    __shared__ float st[DIM];
    __shared__ float stp[HD];
    __shared__ float sv[HD];
    __shared__ float so[HD];
    int b = blockIdx.x, t = threadIdx.x;
    if (b < 256) {                       // coalesced column-sum, 32 rows/block
        if (t < DIM) {
            float acc = 0.f;
            int r0 = b * 32;
            for (int r = 0; r < 32; r++) acc += x[(r0 + r) * DIM + t];
            atomicAdd(&colsum[t], acc);
        }
        return;
    }
    if (b < 272) {                       // per-edge dedupe (set semantics) + counts
        int e = (b - 256) * 256 + t;     // 16*256 == NEDGE exactly
        int idx[DEGREE];
#pragma unroll
        for (int i = 0; i < DEGREE; i++) idx[i] = en[e * DEGREE + i];
        int mask = 0;
#pragma unroll
        for (int i = 0; i < DEGREE; i++) {
            bool uniq = true;
            for (int j = 0; j < i; j++) uniq = uniq && (idx[j] != idx[i]);
            if (uniq) { mask |= (1 << i); atomicAdd(&cnt[idx[i]], 1); }
        }
        emask[e] = mask;
        return;
    }
    if (b < 372) {                       // Wg rows, 2 rows per block
        int r = 2 * (b - 272) + (t >> 7);
        int c = t & 127;
        const float* vec = &W[r * DIM];
        float acc = 0.f;
        for (int k = 0; k < DIM; k++) acc += vec[k] * gnn_w[k * HD + c];
        Wg[r * HD + c] = acc;
        return;
    }
    if (b == 372) {                      // bg = bias @ gnn_w + gnn_b
        if (t < HD) {
            float acc = 0.f;
            for (int k = 0; k < DIM; k++) acc += bias[k] * gnn_w[k * HD + t];
            bg[t] = acc + gnn_b[t];
        }
        return;
    }
    // b == 373: text path. q/k/softmax dead (kv_len==1 -> softmax==1 -> att=v).
    if (t >= HD) return;
    for (int g = 0; g < NB; g++) {
        for (int d = t; d < DIM; d += HD) st[d] = text[g * DIM + d];
        __syncthreads();
        float acc = text_b[t];
        for (int k = 0; k < DIM; k++) acc += st[k] * text_w[k * HD + t];
        stp[t] = acc;
        __syncthreads();
        acc = in_b[2 * HD + t];
        for (int j = 0; j < HD; j++) acc += stp[j] * in_w[j * 3 * HD + 2 * HD + t];
        sv[t] = acc;
        __syncthreads();
        acc = aob[t];
        for (int j = 0; j < HD; j++) acc += sv[j] * aow[j * HD + t];
        so[t] = acc;
        attO[g * HD + t] = acc;
        __syncthreads();
        acc = fgb[t];
        for (int j = 0; j < HD; j++) acc += so[j] * fgw[(HD + j) * HD + t];
        attg[g * HD + t] = acc;
        __syncthreads();
    }
}

// ---- k_mid: block 0 = alpha reduction; block 1 = shuffle scan + dv ----
__global__ void k_mid(const float* __restrict__ colsum, const float* __restrict__ gate_w,
                      const float* __restrict__ gate_b, float* __restrict__ alpha,
                      const int* __restrict__ cnt, int* __restrict__ off,
                      int* __restrict__ cursor, float* __restrict__ dv) {
    __shared__ float redf[1024];
    __shared__ int wsum[16];
    int t = threadIdx.x;
    if (blockIdx.x == 0) {
        redf[t] = (t < DIM) ? colsum[t] * gate_w[t] : 0.f;
        __syncthreads();
        for (int o = 512; o > 0; o >>= 1) {
            if (t < o) redf[t] += redf[t + o];
            __syncthreads();
        }
        if (t == 0) {
            float z = redf[0] / (float)NODES + gate_b[0];
            alpha[0] = 1.0f / (1.0f + expf(-z));
        }
        return;
    }
    // exclusive scan of cnt -> off/cursor; dv = 1/sqrt(cnt/16+eps)
    int base = t * 8;
    int local[8];
    int s = 0;
#pragma unroll
    for (int i = 0; i < 8; i++) { local[i] = cnt[base + i]; s += local[i]; }
    int lane = t & 63, wv = t >> 6;
    int v = s;
    for (int d = 1; d < 64; d <<= 1) {
        int u = __shfl_up(v, d);
        if (lane >= d) v += u;
    }
    if (lane == 63) wsum[wv] = v;
    __syncthreads();
    if (t == 0) {
        int run = 0;
        for (int i = 0; i < 16; i++) { int tmp = wsum[i]; wsum[i] = run; run += tmp; }
    }
    __syncthreads();
    int run = wsum[wv] + v - s;          // global exclusive prefix
#pragma unroll
    for (int i = 0; i < 8; i++) {
        off[base + i] = run;
        cursor[base + i] = run;
        dv[base + i] = 1.0f / sqrtf((float)local[i] * (1.0f / 16.0f) + 1e-8f);
        run += local[i];
    }
    if (t == 1023) off[NODES] = run;
}

// ---- k_xwgfill: blocks 0..1023 = out2 = x@Wg (8-row tiles); 1024..1039 = CSR fill ----
__global__ void k_xwgfill(const float* __restrict__ x, const float* __restrict__ Wg,
                          float* __restrict__ out2, const int* __restrict__ en,
                          const int* __restrict__ emask, int* __restrict__ cursor,
                          int* __restrict__ elist) {
    __shared__ float sx[MT][DIM];
    int t = threadIdx.x;
    if (blockIdx.x >= NODES / MT) {
        int e = (blockIdx.x - NODES / MT) * 256 + t;
        int m = emask[e];
#pragma unroll
        for (int i = 0; i < DEGREE; i++) {
            if ((m >> i) & 1) {
                int n = en[e * DEGREE + i];
                int p = atomicAdd(&cursor[n], 1);
                elist[p] = e;
            }
        }
        return;
    }
    int bm = blockIdx.x * MT;
    for (int i = t; i < MT * DIM; i += 256) sx[i / DIM][i % DIM] = x[bm * DIM + i];
    __syncthreads();
    int c = t & 127, rg = t >> 7;        // 2 row-groups x 128 cols, 4 rows each
    float acc[4] = {0.f, 0.f, 0.f, 0.f};
    for (int k = 0; k < DIM; k++) {
        float w = Wg[k * HD + c];
#pragma unroll
        for (int i = 0; i < 4; i++) acc[i] += sx[rg * 4 + i][k] * w;
    }
#pragma unroll
    for (int i = 0; i < 4; i++) out2[(bm + rg * 4 + i) * HD + c] = acc[i];
}

// ---- tE[e,:] = de[e] * sum_{i in uniq(e)} dv[m_i] * out2[m_i,:] ----
__global__ void k_tE(const int* __restrict__ en, const int* __restrict__ emask,
                     const float* __restrict__ dv, const float* __restrict__ out2,
                     float* __restrict__ tE) {
    int e = blockIdx.x * 2 + (threadIdx.x >> 7);
    int c = threadIdx.x & 127;
    int m = emask[e];
    float De = (float)__popc(m) * (1.0f / 16.0f);
    float de = 1.0f / (De + 1e-8f);
    float acc = 0.f;
#pragma unroll
    for (int i = 0; i < DEGREE; i++) {
        if ((m >> i) & 1) {
            int nd = en[e * DEGREE + i];
            acc += dv[nd] * out2[nd * HD + c];
        }
    }
    tE[e * HD + c] = de * acc;
}

// ---- fused tail, 8-row tiles (1024 blocks):
// LDS-staged elist -> hyper gather -> gp -> gate -> fused -> out = fused@opw+opb
__global__ void k_tail(const float* __restrict__ out2, const float* __restrict__ tE,
                       const float* __restrict__ dv, const int* __restrict__ off,
                       const int* __restrict__ elist, const float* __restrict__ alpha,
                       const float* __restrict__ bg, const float* __restrict__ fgw,
                       const float* __restrict__ attO, const float* __restrict__ attg,
                       const float* __restrict__ opw, const float* __restrict__ opb,
                       float* __restrict__ out) {
    __shared__ float sgp[MT][HD];
    __shared__ int   sl[MT][ECAP];
    __shared__ int   scount[MT];
    int bm = blockIdx.x * MT;
    int b = bm >> 11;                    // graph id (NNODE=2048, tiles don't straddle)
    int t = threadIdx.x;
    // phase 0: stage per-row edge lists into LDS (32 threads per row)
    {
        int r = t >> 5, l = t & 31;
        int n = bm + r;
        int j0 = off[n], j1 = off[n + 1];
        int cc = j1 - j0;
        if (l == 0) scount[r] = cc;
        int lim = cc < ECAP ? cc : ECAP;
        for (int j = l; j < lim; j += 32) sl[r][j] = elist[j0 + j];
    }
    __syncthreads();
    int c = t & 127, rg = t >> 7;
    float a = alpha[0];
    float bgc = bg[c];
    // phase 1: gp rows into LDS (edge ids from LDS -> independent tE loads)
#pragma unroll
    for (int i = 0; i < 4; i++) {
        int r = rg * 4 + i;
        int n = bm + r;
        int cc = scount[r];
        int lim = cc < ECAP ? cc : ECAP;
        float hyp = 0.f;
        for (int j = 0; j < lim; j++) hyp += tE[sl[r][j] * HD + c];
        if (cc > ECAP) {                 // overflow fallback (essentially never)
            int j0 = off[n];
            for (int j = ECAP; j < cc; j++) hyp += tE[elist[j0 + j] * HD + c];
        }
        hyp *= dv[n] * (1.0f / 256.0f);
        sgp[r][c] = a * out2[n * HD + c] + (1.0f - a) * hyp + bgc;
    }
    __syncthreads();
    // phase 2: gate logits (weight element reused across 4 rows)
    float ao = attO[b * HD + c];
    float ag = attg[b * HD + c];
    float acc[4] = {ag, ag, ag, ag};
    for (int j = 0; j < HD; j++) {
        float w = fgw[j * HD + c];
#pragma unroll
        for (int i = 0; i < 4; i++) acc[i] += sgp[rg * 4 + i][j] * w;
    }
    __syncthreads();
    // phase 3: fused = g*gp + (1-g)*attO, in place
#pragma unroll
    for (int i = 0; i < 4; i++) {
        int r = rg * 4 + i;
        float g = 1.0f / (1.0f + expf(-acc[i]));
        sgp[r][c] = g * sgp[r][c] + (1.0f - g) * ao;
    }
    __syncthreads();
    // phase 4: out = fused @ opw + opb (threads 0..199 own one output col)
    if (t < DIM) {
        float accO[MT];
        float ob = opb[t];
#pragma unroll
        for (int i = 0; i < MT; i++) accO[i] = ob;
        for (int j = 0; j < HD; j++) {
            float w = opw[j * DIM + t];
#pragma unroll
            for (int i = 0; i < MT; i++) accO[i] += sgp[i][j] * w;
        }
#pragma unroll
        for (int i = 0; i < MT; i++) out[(bm + i) * DIM + t] = accO[i];
    }
}

extern "C" void kernel_launch(void* const* d_in, const int* in_sizes, int n_in,
                              void* d_out, int out_size, void* d_ws, size_t ws_size,
                              hipStream_t stream) {
    const float* x      = (const float*)d_in[0];
    const float* text   = (const float*)d_in[1];
    const float* W      = (const float*)d_in[2];
    const float* bias   = (const float*)d_in[3];
    const float* gate_w = (const float*)d_in[4];
    const float* gate_b = (const float*)d_in[5];
    const float* gnn_w  = (const float*)d_in[6];
    const float* gnn_b  = (const float*)d_in[7];
    const float* text_w = (const float*)d_in[8];
    const float* text_b = (const float*)d_in[9];
    const float* in_w   = (const float*)d_in[10];
    const float* in_b   = (const float*)d_in[11];
    const float* aow    = (const float*)d_in[12];
    const float* aob    = (const float*)d_in[13];
    const float* fgw    = (const float*)d_in[14];
    const float* fgb    = (const float*)d_in[15];
    const float* opw    = (const float*)d_in[16];
    const float* opb    = (const float*)d_in[17];
    const int*   en     = (const int*)d_in[18];
    float* out = (float*)d_out;

    // Scratch layout (~6.6 MB). cnt+colsum adjacent -> one memset covers both.
    char* p = (char*)d_ws;
    int*   cnt    = (int*)p;   p += NODES * sizeof(int);
    float* colsum = (float*)p; p += DIM * sizeof(float);
    float* out2   = (float*)p; p += (size_t)NODES * HD * sizeof(float);   // 4 MB
    float* tE     = (float*)p; p += (size_t)NEDGE * HD * sizeof(float);   // 2 MB
    float* Wg     = (float*)p; p += DIM * HD * sizeof(float);
    float* dv     = (float*)p; p += NODES * sizeof(float);
    float* alpha  = (float*)p; p += sizeof(float);
    float* bg     = (float*)p; p += HD * sizeof(float);
    float* attO   = (float*)p; p += NB * HD * sizeof(float);
    float* attg   = (float*)p; p += NB * HD * sizeof(float);
    int*   off    = (int*)p;   p += (NODES + 1) * sizeof(int);
    int*   cursor = (int*)p;   p += NODES * sizeof(int);
    int*   emask  = (int*)p;   p += NEDGE * sizeof(int);
    int*   elist  = (int*)p;   p += (size_t)NEDGE * DEGREE * sizeof(int);

    hipMemsetAsync(cnt, 0, (NODES + DIM) * sizeof(int), stream);

    k_front<<<374, 256, 0, stream>>>(x, en, W, gnn_w, bias, gnn_b, text, text_w,
                                     text_b, in_w, in_b, aow, aob, fgw, fgb,
                                     colsum, cnt, emask, Wg, bg, attO, attg);
    k_mid<<<2, 1024, 0, stream>>>(colsum, gate_w, gate_b, alpha, cnt, off, cursor, dv);
    k_xwgfill<<<NODES / MT + 16, 256, 0, stream>>>(x, Wg, out2, en, emask, cursor, elist);
    k_tE<<<NEDGE / 2, 256, 0, stream>>>(en, emask, dv, out2, tE);
    k_tail<<<NODES / MT, 256, 0, stream>>>(out2, tE, dv, off, elist, alpha, bg, fgw,
                                           attO, attg, opw, opb, out);
}

// Round 6
// 173.917 us; speedup vs baseline: 2.0182x; 1.2283x over previous
//
#include <hip/hip_runtime.h>
#include <hip/hip_bf16.h>

// Problem dims (fixed by setup_inputs)
#define NODES 8192
#define DIM   200
#define NEDGE 4096
#define DEGREE 16
#define NB    4
#define NNODE 2048   // nodes per graph = NODES/NB
#define HD    128
#define MT    8      // row tile (8 rows/block -> 1024 blocks -> 4 wg/CU)
#define ECAP  64     // LDS cap for per-row edge list (avg 8, Poisson tail << 64)

// ---- k_front: colsum (blocks 0..255) + edge count/dedupe (256..271)
// ----          + Wg = W@gnn_w rows (272..371) + bg (372) + text path (373..376)
__global__ void k_front(const float* __restrict__ x, const int* __restrict__ en,
                        const float* __restrict__ W, const float* __restrict__ gnn_w,
                        const float* __restrict__ bias, const float* __restrict__ gnn_b,
                        const float* __restrict__ text, const float* __restrict__ text_w,
                        const float* __restrict__ text_b, const float* __restrict__ in_w,
                        const float* __restrict__ in_b, const float* __restrict__ aow,
                        const float* __restrict__ aob, const float* __restrict__ fgw,
                        const float* __restrict__ fgb, float* __restrict__ colsum,
                        int* __restrict__ cnt, int* __restrict__ emask,
                        float* __restrict__ Wg, float* __restrict__ bg,
                        float* __restrict__ attO, float* __restrict__ attg) {
    __shared__ float st[DIM];
    __shared__ float part[2][HD];
    __shared__ float vin[HD];
    int b = blockIdx.x, t = threadIdx.x;
    if (b < 256) {                       // coalesced column-sum, 32 rows/block
        if (t < DIM) {
            float acc = 0.f;
            int r0 = b * 32;
            for (int r = 0; r < 32; r++) acc += x[(r0 + r) * DIM + t];
            atomicAdd(&colsum[t], acc);
        }
        return;
    }
    if (b < 272) {                       // per-edge dedupe (set semantics) + counts
        int e = (b - 256) * 256 + t;     // 16*256 == NEDGE exactly
        int idx[DEGREE];
#pragma unroll
        for (int i = 0; i < DEGREE; i++) idx[i] = en[e * DEGREE + i];
        int mask = 0;
#pragma unroll
        for (int i = 0; i < DEGREE; i++) {
            bool uniq = true;
            for (int j = 0; j < i; j++) uniq = uniq && (idx[j] != idx[i]);
            if (uniq) { mask |= (1 << i); atomicAdd(&cnt[idx[i]], 1); }
        }
        emask[e] = mask;
        return;
    }
    if (b < 372) {                       // Wg rows, 2 rows per block
        int r = 2 * (b - 272) + (t >> 7);
        int c = t & 127;
        const float* vec = &W[r * DIM];
        float acc = 0.f;
        for (int k = 0; k < DIM; k++) acc += vec[k] * gnn_w[k * HD + c];
        Wg[r * HD + c] = acc;
        return;
    }
    if (b == 372) {                      // bg = bias @ gnn_w + gnn_b
        if (t < HD) {
            float acc = 0.f;
            for (int k = 0; k < DIM; k++) acc += bias[k] * gnn_w[k * HD + t];
            bg[t] = acc + gnn_b[t];
        }
        return;
    }
    // b in [373,377): text path for graph g, k-parallel GEMV chain.
    // q/k/softmax dead (kv_len==1 -> softmax==1 -> att = v broadcast).
    int g = b - 373;
    int c = t & 127, h = t >> 7;
    if (t < DIM) st[t] = text[g * DIM + t];
    __syncthreads();
    // tp = text @ text_w + text_b   (k=200, split 100/100)
    {
        float acc = 0.f;
        int k0 = h * 100;
        for (int k = k0; k < k0 + 100; k++) acc += st[k] * text_w[k * HD + c];
        part[h][c] = acc;
    }
    __syncthreads();
    if (t < HD) vin[t] = part[0][t] + part[1][t] + text_b[t];
    __syncthreads();
    // v = tp @ in_w[:, 2H:3H] + in_b[2H:3H]   (k=128, split 64/64)
    {
        float acc = 0.f;
        int k0 = h * 64;
        for (int k = k0; k < k0 + 64; k++) acc += vin[k] * in_w[k * 3 * HD + 2 * HD + c];
        part[h][c] = acc;
    }
    __syncthreads();
    if (t < HD) vin[t] = part[0][t] + part[1][t] + in_b[2 * HD + t];
    __syncthreads();
    // attO = v @ aow + aob
    {
        float acc = 0.f;
        int k0 = h * 64;
        for (int k = k0; k < k0 + 64; k++) acc += vin[k] * aow[k * HD + c];
        part[h][c] = acc;
    }
    __syncthreads();
    if (t < HD) {
        float ao = part[0][t] + part[1][t] + aob[t];
        attO[g * HD + t] = ao;
        vin[t] = ao;
    }
    __syncthreads();
    // attg = attO @ fgw[H:2H, :] + fgb
    {
        float acc = 0.f;
        int k0 = h * 64;
        for (int k = k0; k < k0 + 64; k++) acc += vin[k] * fgw[(HD + k) * HD + c];
        part[h][c] = acc;
    }
    __syncthreads();
    if (t < HD) attg[g * HD + t] = part[0][t] + part[1][t] + fgb[t];
}

// ---- k_mid: block 0 = alpha reduction; block 1 = shuffle scan + dv ----
__global__ void k_mid(const float* __restrict__ colsum, const float* __restrict__ gate_w,
                      const float* __restrict__ gate_b, float* __restrict__ alpha,
                      const int* __restrict__ cnt, int* __restrict__ off,
                      int* __restrict__ cursor, float* __restrict__ dv) {
    __shared__ float redf[1024];
    __shared__ int wsum[16];
    int t = threadIdx.x;
    if (blockIdx.x == 0) {
        redf[t] = (t < DIM) ? colsum[t] * gate_w[t] : 0.f;
        __syncthreads();
        for (int o = 512; o > 0; o >>= 1) {
            if (t < o) redf[t] += redf[t + o];
            __syncthreads();
        }
        if (t == 0) {
            float z = redf[0] / (float)NODES + gate_b[0];
            alpha[0] = 1.0f / (1.0f + expf(-z));
        }
        return;
    }
    // exclusive scan of cnt -> off/cursor; dv = 1/sqrt(cnt/16+eps)
    int base = t * 8;
    int local[8];
    int s = 0;
#pragma unroll
    for (int i = 0; i < 8; i++) { local[i] = cnt[base + i]; s += local[i]; }
    int lane = t & 63, wv = t >> 6;
    int v = s;
    for (int d = 1; d < 64; d <<= 1) {
        int u = __shfl_up(v, d);
        if (lane >= d) v += u;
    }
    if (lane == 63) wsum[wv] = v;
    __syncthreads();
    if (t == 0) {
        int run = 0;
        for (int i = 0; i < 16; i++) { int tmp = wsum[i]; wsum[i] = run; run += tmp; }
    }
    __syncthreads();
    int run = wsum[wv] + v - s;          // global exclusive prefix
#pragma unroll
    for (int i = 0; i < 8; i++) {
        off[base + i] = run;
        cursor[base + i] = run;
        dv[base + i] = 1.0f / sqrtf((float)local[i] * (1.0f / 16.0f) + 1e-8f);
        run += local[i];
    }
    if (t == 1023) off[NODES] = run;
}

// ---- k_xwgfill: blocks 0..1023 = out2 = x@Wg (8-row tiles); 1024..1039 = CSR fill ----
__global__ void k_xwgfill(const float* __restrict__ x, const float* __restrict__ Wg,
                          float* __restrict__ out2, const int* __restrict__ en,
                          const int* __restrict__ emask, int* __restrict__ cursor,
                          int* __restrict__ elist) {
    __shared__ float sx[MT][DIM];
    int t = threadIdx.x;
    if (blockIdx.x >= NODES / MT) {
        int e = (blockIdx.x - NODES / MT) * 256 + t;
        int m = emask[e];
#pragma unroll
        for (int i = 0; i < DEGREE; i++) {
            if ((m >> i) & 1) {
                int n = en[e * DEGREE + i];
                int p = atomicAdd(&cursor[n], 1);
                elist[p] = e;
            }
        }
        return;
    }
    int bm = blockIdx.x * MT;
    for (int i = t; i < MT * DIM; i += 256) sx[i / DIM][i % DIM] = x[bm * DIM + i];
    __syncthreads();
    int c = t & 127, rg = t >> 7;        // 2 row-groups x 128 cols, 4 rows each
    float acc[4] = {0.f, 0.f, 0.f, 0.f};
    for (int k = 0; k < DIM; k++) {
        float w = Wg[k * HD + c];
#pragma unroll
        for (int i = 0; i < 4; i++) acc[i] += sx[rg * 4 + i][k] * w;
    }
#pragma unroll
    for (int i = 0; i < 4; i++) out2[(bm + rg * 4 + i) * HD + c] = acc[i];
}

// ---- tE[e,:] = de[e] * sum_{i in uniq(e)} dv[m_i] * out2[m_i,:] ----
__global__ void k_tE(const int* __restrict__ en, const int* __restrict__ emask,
                     const float* __restrict__ dv, const float* __restrict__ out2,
                     float* __restrict__ tE) {
    int e = blockIdx.x * 2 + (threadIdx.x >> 7);
    int c = threadIdx.x & 127;
    int m = emask[e];
    float De = (float)__popc(m) * (1.0f / 16.0f);
    float de = 1.0f / (De + 1e-8f);
    float acc = 0.f;
#pragma unroll
    for (int i = 0; i < DEGREE; i++) {
        if ((m >> i) & 1) {
            int nd = en[e * DEGREE + i];
            acc += dv[nd] * out2[nd * HD + c];
        }
    }
    tE[e * HD + c] = de * acc;
}

// ---- fused tail, 8-row tiles (1024 blocks):
// LDS-staged elist -> hyper gather -> gp -> gate -> fused -> out = fused@opw+opb
__global__ void k_tail(const float* __restrict__ out2, const float* __restrict__ tE,
                       const float* __restrict__ dv, const int* __restrict__ off,
                       const int* __restrict__ elist, const float* __restrict__ alpha,
                       const float* __restrict__ bg, const float* __restrict__ fgw,
                       const float* __restrict__ attO, const float* __restrict__ attg,
                       const float* __restrict__ opw, const float* __restrict__ opb,
                       float* __restrict__ out) {
    __shared__ float sgp[MT][HD];
    __shared__ int   sl[MT][ECAP];
    __shared__ int   scount[MT];
    int bm = blockIdx.x * MT;
    int b = bm >> 11;                    // graph id (NNODE=2048, tiles don't straddle)
    int t = threadIdx.x;
    // phase 0: stage per-row edge lists into LDS (32 threads per row)
    {
        int r = t >> 5, l = t & 31;
        int n = bm + r;
        int j0 = off[n], j1 = off[n + 1];
        int cc = j1 - j0;
        if (l == 0) scount[r] = cc;
        int lim = cc < ECAP ? cc : ECAP;
        for (int j = l; j < lim; j += 32) sl[r][j] = elist[j0 + j];
    }
    __syncthreads();
    int c = t & 127, rg = t >> 7;
    float a = alpha[0];
    float bgc = bg[c];
    // phase 1: gp rows into LDS (edge ids from LDS -> independent tE loads)
#pragma unroll
    for (int i = 0; i < 4; i++) {
        int r = rg * 4 + i;
        int n = bm + r;
        int cc = scount[r];
        int lim = cc < ECAP ? cc : ECAP;
        float hyp = 0.f;
        for (int j = 0; j < lim; j++) hyp += tE[sl[r][j] * HD + c];
        if (cc > ECAP) {                 // overflow fallback (essentially never)
            int j0 = off[n];
            for (int j = ECAP; j < cc; j++) hyp += tE[elist[j0 + j] * HD + c];
        }
        hyp *= dv[n] * (1.0f / 256.0f);
        sgp[r][c] = a * out2[n * HD + c] + (1.0f - a) * hyp + bgc;
    }
    __syncthreads();
    // phase 2: gate logits (weight element reused across 4 rows)
    float ao = attO[b * HD + c];
    float ag = attg[b * HD + c];
    float acc[4] = {ag, ag, ag, ag};
    for (int j = 0; j < HD; j++) {
        float w = fgw[j * HD + c];
#pragma unroll
        for (int i = 0; i < 4; i++) acc[i] += sgp[rg * 4 + i][j] * w;
    }
    __syncthreads();
    // phase 3: fused = g*gp + (1-g)*attO, in place
#pragma unroll
    for (int i = 0; i < 4; i++) {
        int r = rg * 4 + i;
        float g = 1.0f / (1.0f + expf(-acc[i]));
        sgp[r][c] = g * sgp[r][c] + (1.0f - g) * ao;
    }
    __syncthreads();
    // phase 4: out = fused @ opw + opb (threads 0..199 own one output col)
    if (t < DIM) {
        float accO[MT];
        float ob = opb[t];
#pragma unroll
        for (int i = 0; i < MT; i++) accO[i] = ob;
        for (int j = 0; j < HD; j++) {
            float w = opw[j * DIM + t];
#pragma unroll
            for (int i = 0; i < MT; i++) accO[i] += sgp[i][j] * w;
        }
#pragma unroll
        for (int i = 0; i < MT; i++) out[(bm + i) * DIM + t] = accO[i];
    }
}

extern "C" void kernel_launch(void* const* d_in, const int* in_sizes, int n_in,
                              void* d_out, int out_size, void* d_ws, size_t ws_size,
                              hipStream_t stream) {
    const float* x      = (const float*)d_in[0];
    const float* text   = (const float*)d_in[1];
    const float* W      = (const float*)d_in[2];
    const float* bias   = (const float*)d_in[3];
    const float* gate_w = (const float*)d_in[4];
    const float* gate_b = (const float*)d_in[5];
    const float* gnn_w  = (const float*)d_in[6];
    const float* gnn_b  = (const float*)d_in[7];
    const float* text_w = (const float*)d_in[8];
    const float* text_b = (const float*)d_in[9];
    const float* in_w   = (const float*)d_in[10];
    const float* in_b   = (const float*)d_in[11];
    const float* aow    = (const float*)d_in[12];
    const float* aob    = (const float*)d_in[13];
    const float* fgw    = (const float*)d_in[14];
    const float* fgb    = (const float*)d_in[15];
    const float* opw    = (const float*)d_in[16];
    const float* opb    = (const float*)d_in[17];
    const int*   en     = (const int*)d_in[18];
    float* out = (float*)d_out;

    // Scratch layout (~6.6 MB). cnt+colsum adjacent -> one memset covers both.
    char* p = (char*)d_ws;
    int*   cnt    = (int*)p;   p += NODES * sizeof(int);
    float* colsum = (float*)p; p += DIM * sizeof(float);
    float* out2   = (float*)p; p += (size_t)NODES * HD * sizeof(float);   // 4 MB
    float* tE     = (float*)p; p += (size_t)NEDGE * HD * sizeof(float);   // 2 MB
    float* Wg     = (float*)p; p += DIM * HD * sizeof(float);
    float* dv     = (float*)p; p += NODES * sizeof(float);
    float* alpha  = (float*)p; p += sizeof(float);
    float* bg     = (float*)p; p += HD * sizeof(float);
    float* attO   = (float*)p; p += NB * HD * sizeof(float);
    float* attg   = (float*)p; p += NB * HD * sizeof(float);
    int*   off    = (int*)p;   p += (NODES + 1) * sizeof(int);
    int*   cursor = (int*)p;   p += NODES * sizeof(int);
    int*   emask  = (int*)p;   p += NEDGE * sizeof(int);
    int*   elist  = (int*)p;   p += (size_t)NEDGE * DEGREE * sizeof(int);

    hipMemsetAsync(cnt, 0, (NODES + DIM) * sizeof(int), stream);

    k_front<<<377, 256, 0, stream>>>(x, en, W, gnn_w, bias, gnn_b, text, text_w,
                                     text_b, in_w, in_b, aow, aob, fgw, fgb,
                                     colsum, cnt, emask, Wg, bg, attO, attg);
    k_mid<<<2, 1024, 0, stream>>>(colsum, gate_w, gate_b, alpha, cnt, off, cursor, dv);
    k_xwgfill<<<NODES / MT + 16, 256, 0, stream>>>(x, Wg, out2, en, emask, cursor, elist);
    k_tE<<<NEDGE / 2, 256, 0, stream>>>(en, emask, dv, out2, tE);
    k_tail<<<NODES / MT, 256, 0, stream>>>(out2, tE, dv, off, elist, alpha, bg, fgw,
                                           attO, attg, opw, opb, out);
}